// Round 3
// baseline (309.493 us; speedup 1.0000x reference)
//
#include <hip/hip_runtime.h>

// FrequencyAwareEmbedding on MI355X.
// Strategy:
//   Kernel 1 (build): resolve every embedding id e in [0,100000) to its final
//     32-float output row TBL[e] in workspace (copy for buckets 0-2, matvec
//     through W3/W4 + bias for buckets 3/4). 32 lanes per row, W in LDS,
//     row values broadcast via segment-local shuffles.
//   Kernel 2 (gather): out[tok] = TBL[x[tok]] as float4, 8 lanes per token.
//     Branch-free, coalesced; TBL (12.8 MB) is L2/L3 resident.

#define NUM_EMB_C 100000
#define BASE_DIM_C 32

__global__ __launch_bounds__(256) void fae_build_table(
    const int* __restrict__ bucket,
    const float* __restrict__ e0, const float* __restrict__ e1,
    const float* __restrict__ e2, const float* __restrict__ e3,
    const float* __restrict__ e4,
    const float* __restrict__ W3, const float* __restrict__ b3,
    const float* __restrict__ W4, const float* __restrict__ b4,
    float* __restrict__ tbl, int num_emb)
{
    __shared__ float w3[51 * 32];
    __shared__ float w4[102 * 32];
    for (int i = threadIdx.x; i < 51 * 32; i += 256) w3[i] = W3[i];
    for (int i = threadIdx.x; i < 102 * 32; i += 256) w4[i] = W4[i];
    __syncthreads();

    const int lane = threadIdx.x & 31;   // output dim d
    const int grp  = threadIdx.x >> 5;   // 8 rows per block
    const int e = blockIdx.x * 8 + grp;
    if (e >= num_emb) return;

    const int bk = bucket[e];
    float val;
    if (bk == 0) {
        val = e0[(size_t)e * 32 + lane];
    } else if (bk == 1) {
        val = e1[(size_t)e * 32 + lane];
    } else if (bk == 2) {
        val = e2[(size_t)e * 32 + lane];
    } else if (bk == 3) {
        const float* row = e3 + (size_t)e * 51;        // 51 floats
        float h0 = row[lane];                           // k = 0..31
        float h1 = (lane < 19) ? row[32 + lane] : 0.f;  // k = 32..50
        float acc = b3[lane];
        #pragma unroll
        for (int k = 0; k < 32; ++k)
            acc = fmaf(__shfl(h0, k, 32), w3[k * 32 + lane], acc);
        #pragma unroll
        for (int k = 0; k < 19; ++k)
            acc = fmaf(__shfl(h1, k, 32), w3[(32 + k) * 32 + lane], acc);
        val = acc;
    } else {
        const float* row = e4 + (size_t)e * 102;       // 102 floats
        float h0 = row[lane];
        float h1 = row[32 + lane];
        float h2 = row[64 + lane];
        float h3 = (lane < 6) ? row[96 + lane] : 0.f;  // k = 96..101
        float acc = b4[lane];
        #pragma unroll
        for (int k = 0; k < 32; ++k)
            acc = fmaf(__shfl(h0, k, 32), w4[k * 32 + lane], acc);
        #pragma unroll
        for (int k = 0; k < 32; ++k)
            acc = fmaf(__shfl(h1, k, 32), w4[(32 + k) * 32 + lane], acc);
        #pragma unroll
        for (int k = 0; k < 32; ++k)
            acc = fmaf(__shfl(h2, k, 32), w4[(64 + k) * 32 + lane], acc);
        #pragma unroll
        for (int k = 0; k < 6; ++k)
            acc = fmaf(__shfl(h3, k, 32), w4[(96 + k) * 32 + lane], acc);
        val = acc;
    }
    tbl[(size_t)e * 32 + lane] = val;
}

__global__ __launch_bounds__(256) void fae_gather(
    const int* __restrict__ x, const float4* __restrict__ tbl,
    float4* __restrict__ out, int n4)
{
    int gid = blockIdx.x * 256 + threadIdx.x;
    if (gid >= n4) return;
    int xi = x[gid >> 3];                       // 8 lanes share a token
    out[gid] = tbl[(size_t)xi * 8 + (gid & 7)]; // one float4 of the row
}

extern "C" void kernel_launch(void* const* d_in, const int* in_sizes, int n_in,
                              void* d_out, int out_size, void* d_ws, size_t ws_size,
                              hipStream_t stream) {
    const int*   x      = (const int*)d_in[0];
    const int*   bucket = (const int*)d_in[1];
    const float* e0     = (const float*)d_in[2];
    const float* e1     = (const float*)d_in[3];
    const float* e2     = (const float*)d_in[4];
    const float* e3     = (const float*)d_in[5];
    const float* e4     = (const float*)d_in[6];
    const float* W3     = (const float*)d_in[7];
    const float* b3     = (const float*)d_in[8];
    const float* W4     = (const float*)d_in[9];
    const float* b4     = (const float*)d_in[10];

    const int num_emb = in_sizes[1];            // 100000
    float* tbl = (float*)d_ws;                  // num_emb * 32 floats = 12.8 MB

    int build_blocks = (num_emb + 7) / 8;       // 8 rows per 256-thread block
    fae_build_table<<<build_blocks, 256, 0, stream>>>(
        bucket, e0, e1, e2, e3, e4, W3, b3, W4, b4, tbl, num_emb);

    int n4 = out_size / 4;                      // float4 elements of out
    int gather_blocks = (n4 + 255) / 256;
    fae_gather<<<gather_blocks, 256, 0, stream>>>(
        x, (const float4*)tbl, (float4*)d_out, n4);
}

// Round 5
// 262.948 us; speedup vs baseline: 1.1770x; 1.1770x over previous
//
#include <hip/hip_runtime.h>

// FrequencyAwareEmbedding on MI355X — v2.
// Build kernel redesigned after r3 counters showed it LDS-pipe bound
// (VALUBusy 15%, HBM 3.6%): the old matvec paid ds_bpermute + ds_read per
// FMA. Now: one embedding per wave (uniform bucket -> scalar branch),
// W columns resident in VGPRs (~77/lane), row values via uniform-address
// VMEM broadcast, k split across wave halves, single shfl_xor reduce.
// Gather: out[tok] = TBL[x[tok]] as float4, nontemporal stores.

typedef float f32x4 __attribute__((ext_vector_type(4)));

__global__ __launch_bounds__(256) void fae_build_v2(
    const int* __restrict__ bucket,
    const float* __restrict__ e0, const float* __restrict__ e1,
    const float* __restrict__ e2, const float* __restrict__ e3,
    const float* __restrict__ e4,
    const float* __restrict__ W3, const float* __restrict__ b3,
    const float* __restrict__ W4, const float* __restrict__ b4,
    float* __restrict__ tbl, int num_emb)
{
    const int lane = threadIdx.x & 63;
    const int d    = lane & 31;   // output dim
    const int h    = lane >> 5;   // k-half owner
    int wid = (int)(blockIdx.x * (blockDim.x >> 6) + (threadIdx.x >> 6));
    wid = __builtin_amdgcn_readfirstlane(wid);            // wave-uniform
    const int nw = (int)(gridDim.x * (blockDim.x >> 6));

    // Per-lane W columns in registers (preload once, amortized over
    // ~num_emb/nw embeddings). Half h owns:
    //   W4: k = h*51 + j, j in [0,51)
    //   W3: k = h*26 + j, j in [0,26); k>=51 -> zero tap (h=1 has 25)
    float w4r[51];
#pragma unroll
    for (int j = 0; j < 51; ++j) w4r[j] = W4[(h * 51 + j) * 32 + d];
    float w3r[26];
#pragma unroll
    for (int j = 0; j < 26; ++j) {
        int k = h * 26 + j;
        w3r[j] = (k < 51) ? W3[k * 32 + d] : 0.0f;
    }
    const float bias3 = b3[d];
    const float bias4 = b4[d];

    for (int e = wid; e < num_emb; e += nw) {
        const int bk = __builtin_amdgcn_readfirstlane(bucket[e]);
        if (bk < 3) {
            const float* src = (bk == 0) ? e0 : (bk == 1) ? e1 : e2;
            if (h == 0) tbl[(size_t)e * 32 + d] = src[(size_t)e * 32 + d];
        } else if (bk == 3) {
            const float* row = e3 + (size_t)e * 51 + h * 26;
            float a0 = h ? 0.0f : bias3;   // bias counted once
            float a1 = 0.0f;
#pragma unroll
            for (int j = 0; j < 26; ++j) {
                // h=1,j=25 is a zero tap; clamp the load so we never read
                // past the last row of e3.
                int jj = (h && (j == 25)) ? 24 : j;
                float rv = row[jj];
                if (j & 1) a1 = fmaf(rv, w3r[j], a1);
                else       a0 = fmaf(rv, w3r[j], a0);
            }
            float acc = a0 + a1;
            acc += __shfl_xor(acc, 32, 64);   // combine k-halves
            if (h == 0) tbl[(size_t)e * 32 + d] = acc;
        } else {
            const float* row = e4 + (size_t)e * 102 + h * 51;
            float a0 = h ? 0.0f : bias4;
            float a1 = 0.0f;
#pragma unroll
            for (int j = 0; j < 51; ++j) {
                float rv = row[j];
                if (j & 1) a1 = fmaf(rv, w4r[j], a1);
                else       a0 = fmaf(rv, w4r[j], a0);
            }
            float acc = a0 + a1;
            acc += __shfl_xor(acc, 32, 64);
            if (h == 0) tbl[(size_t)e * 32 + d] = acc;
        }
    }
}

__global__ __launch_bounds__(256) void fae_gather(
    const int* __restrict__ x, const f32x4* __restrict__ tbl,
    f32x4* __restrict__ out, int n4)
{
    int gid = blockIdx.x * 256 + threadIdx.x;
    if (gid >= n4) return;
    int xi = x[gid >> 3];                       // 8 lanes share a token
    f32x4 v = tbl[(size_t)xi * 8 + (gid & 7)];  // one float4 of the row
    __builtin_nontemporal_store(v, out + gid);  // write-once stream
}

extern "C" void kernel_launch(void* const* d_in, const int* in_sizes, int n_in,
                              void* d_out, int out_size, void* d_ws, size_t ws_size,
                              hipStream_t stream) {
    const int*   x      = (const int*)d_in[0];
    const int*   bucket = (const int*)d_in[1];
    const float* e0     = (const float*)d_in[2];
    const float* e1     = (const float*)d_in[3];
    const float* e2     = (const float*)d_in[4];
    const float* e3     = (const float*)d_in[5];
    const float* e4     = (const float*)d_in[6];
    const float* W3     = (const float*)d_in[7];
    const float* b3     = (const float*)d_in[8];
    const float* W4     = (const float*)d_in[9];
    const float* b4     = (const float*)d_in[10];

    const int num_emb = in_sizes[1];            // 100000
    float* tbl = (float*)d_ws;                  // num_emb * 32 floats = 12.8 MB

    // 1024 blocks x 4 waves = 4096 waves, ~24 embeddings each (grid-stride).
    fae_build_v2<<<1024, 256, 0, stream>>>(
        bucket, e0, e1, e2, e3, e4, W3, b3, W4, b4, tbl, num_emb);

    int n4 = out_size / 4;                      // float4 elements of out
    int gather_blocks = (n4 + 255) / 256;
    fae_gather<<<gather_blocks, 256, 0, stream>>>(
        x, (const f32x4*)tbl, (f32x4*)d_out, n4);
}

// Round 7
// 262.103 us; speedup vs baseline: 1.1808x; 1.0032x over previous
//
#include <hip/hip_runtime.h>

// FrequencyAwareEmbedding on MI355X — v3.
// r5 post-mortem: build v2 (~41us inferred) was cold-miss latency-serial:
// grid-stride gave each wave embeddings 4096 apart, so every bucket[] load
// and every e3/e4 row was its own ~900cy HBM miss, serialized by the
// bucket->branch->row dependence. v3 assigns each wave a CONTIGUOUS chunk:
// bucket loads are L1-sequential, row reads are forward streams.
// Weights remain in VGPRs (r3 showed LDS-pipe bound with ds ops per FMA).
// Gather unchanged from v2 for attribution.

typedef float f32x4 __attribute__((ext_vector_type(4)));

__global__ __launch_bounds__(256) void fae_build_v3(
    const int* __restrict__ bucket,
    const float* __restrict__ e0, const float* __restrict__ e1,
    const float* __restrict__ e2, const float* __restrict__ e3,
    const float* __restrict__ e4,
    const float* __restrict__ W3, const float* __restrict__ b3,
    const float* __restrict__ W4, const float* __restrict__ b4,
    float* __restrict__ tbl, int num_emb)
{
    const int lane = threadIdx.x & 63;
    const int d    = lane & 31;   // output dim
    const int h    = lane >> 5;   // k-half owner
    int wid = (int)(blockIdx.x * (blockDim.x >> 6) + (threadIdx.x >> 6));
    wid = __builtin_amdgcn_readfirstlane(wid);            // wave-uniform
    const int nw = (int)(gridDim.x * (blockDim.x >> 6));

    // Contiguous chunk [e0i, e1i) per wave: sequential bucket loads (L1-hit
    // after first line), streaming row reads.
    const int chunk = (num_emb + nw - 1) / nw;
    const int eBeg  = wid * chunk;
    const int eEnd  = (eBeg + chunk < num_emb) ? (eBeg + chunk) : num_emb;

    // Per-lane W columns in registers (preload once per wave; W itself is
    // 19.6KB total -> L2-resident across waves). Half h owns:
    //   W4: k = h*51 + j, j in [0,51)
    //   W3: k = h*26 + j, j in [0,26); k>=51 -> zero tap (h=1 has 25)
    float w4r[51];
#pragma unroll
    for (int j = 0; j < 51; ++j) w4r[j] = W4[(h * 51 + j) * 32 + d];
    float w3r[26];
#pragma unroll
    for (int j = 0; j < 26; ++j) {
        int k = h * 26 + j;
        w3r[j] = (k < 51) ? W3[k * 32 + d] : 0.0f;
    }
    const float bias3 = b3[d];
    const float bias4 = b4[d];

    for (int e = eBeg; e < eEnd; ++e) {
        const int bk = __builtin_amdgcn_readfirstlane(bucket[e]);
        if (bk < 3) {
            const float* src = (bk == 0) ? e0 : (bk == 1) ? e1 : e2;
            if (h == 0) tbl[(size_t)e * 32 + d] = src[(size_t)e * 32 + d];
        } else if (bk == 3) {
            const float* row = e3 + (size_t)e * 51 + h * 26;
            float a0 = h ? 0.0f : bias3;   // bias counted once
            float a1 = 0.0f;
#pragma unroll
            for (int j = 0; j < 26; ++j) {
                // h=1,j=25 is a zero tap; clamp the load so we never read
                // past the last row of e3.
                int jj = (h && (j == 25)) ? 24 : j;
                float rv = row[jj];
                if (j & 1) a1 = fmaf(rv, w3r[j], a1);
                else       a0 = fmaf(rv, w3r[j], a0);
            }
            float acc = a0 + a1;
            acc += __shfl_xor(acc, 32, 64);   // combine k-halves
            if (h == 0) tbl[(size_t)e * 32 + d] = acc;
        } else {
            const float* row = e4 + (size_t)e * 102 + h * 51;
            float a0 = h ? 0.0f : bias4;
            float a1 = 0.0f;
#pragma unroll
            for (int j = 0; j < 51; ++j) {
                float rv = row[j];
                if (j & 1) a1 = fmaf(rv, w4r[j], a1);
                else       a0 = fmaf(rv, w4r[j], a0);
            }
            float acc = a0 + a1;
            acc += __shfl_xor(acc, 32, 64);
            if (h == 0) tbl[(size_t)e * 32 + d] = acc;
        }
    }
}

__global__ __launch_bounds__(256) void fae_gather(
    const int* __restrict__ x, const f32x4* __restrict__ tbl,
    f32x4* __restrict__ out, int n4)
{
    int gid = blockIdx.x * 256 + threadIdx.x;
    if (gid >= n4) return;
    int xi = x[gid >> 3];                       // 8 lanes share a token
    f32x4 v = tbl[(size_t)xi * 8 + (gid & 7)];  // one float4 of the row
    __builtin_nontemporal_store(v, out + gid);  // write-once stream
}

extern "C" void kernel_launch(void* const* d_in, const int* in_sizes, int n_in,
                              void* d_out, int out_size, void* d_ws, size_t ws_size,
                              hipStream_t stream) {
    const int*   x      = (const int*)d_in[0];
    const int*   bucket = (const int*)d_in[1];
    const float* e0     = (const float*)d_in[2];
    const float* e1     = (const float*)d_in[3];
    const float* e2     = (const float*)d_in[4];
    const float* e3     = (const float*)d_in[5];
    const float* e4     = (const float*)d_in[6];
    const float* W3     = (const float*)d_in[7];
    const float* b3     = (const float*)d_in[8];
    const float* W4     = (const float*)d_in[9];
    const float* b4     = (const float*)d_in[10];

    const int num_emb = in_sizes[1];            // 100000
    float* tbl = (float*)d_ws;                  // num_emb * 32 floats = 12.8 MB

    // 1024 blocks x 4 waves = 4096 waves, ~25 contiguous embeddings each.
    fae_build_v3<<<1024, 256, 0, stream>>>(
        bucket, e0, e1, e2, e3, e4, W3, b3, W4, b4, tbl, num_emb);

    int n4 = out_size / 4;                      // float4 elements of out
    int gather_blocks = (n4 + 255) / 256;
    fae_gather<<<gather_blocks, 256, 0, stream>>>(
        x, (const f32x4*)tbl, (f32x4*)d_out, n4);
}